// Round 2
// baseline (381.291 us; speedup 1.0000x reference)
//
#include <hip/hip_runtime.h>
#include <stdint.h>

#define DEVINL __device__ __forceinline__

typedef float  f32x4 __attribute__((ext_vector_type(4)));
typedef short  s16x8 __attribute__((ext_vector_type(8)));
typedef unsigned short u16x8 __attribute__((ext_vector_type(8)));

static constexpr int Bb = 2, S = 2048, D = 1024, H = 16, DK = 64;
static constexpr size_t OUT0 = (size_t)Bb * S * D;   // 4194304

DEVINL unsigned short f2bf(float f) {
  union { float f; unsigned u; } v; v.f = f;
  unsigned r = v.u + 0x7FFFu + ((v.u >> 16) & 1u);   // RNE
  return (unsigned short)(r >> 16);
}

DEVINL void gload_lds16(const void* g, void* l) {
  __builtin_amdgcn_global_load_lds(
      (const __attribute__((address_space(1))) unsigned int*)g,
      (__attribute__((address_space(3))) unsigned int*)l, 16, 0, 0);
}

// ---------------- fp32 -> bf16 convert, 8 elems/thread ----------------
__global__ __launch_bounds__(256) void k_cvt(const float* __restrict__ src,
                                             unsigned short* __restrict__ dst, int n8) {
  int i = blockIdx.x * 256 + threadIdx.x;
  if (i >= n8) return;
  const f32x4* s4 = (const f32x4*)src;
  f32x4 a = s4[i * 2], b = s4[i * 2 + 1];
  u16x8 o;
  o[0] = f2bf(a[0]); o[1] = f2bf(a[1]); o[2] = f2bf(a[2]); o[3] = f2bf(a[3]);
  o[4] = f2bf(b[0]); o[5] = f2bf(b[1]); o[6] = f2bf(b[2]); o[7] = f2bf(b[3]);
  ((u16x8*)dst)[i] = o;
}

// ---------------- GEMM: C[M=4096,N=1024] = A[M,K=1024] @ Bw[N,K]^T + bias ---
// MODE 0: write bf16 to [b,h,s,d] layout (QKV proj).  MODE 1: fp32 row-major.
template <int MODE>
__global__ __launch_bounds__(256) void k_gemm(const unsigned short* __restrict__ A,
                                              const unsigned short* __restrict__ Bw,
                                              const float* __restrict__ bias,
                                              void* __restrict__ Cout) {
  __shared__ alignas(16) unsigned short As[128 * 32];
  __shared__ alignas(16) unsigned short Bs[128 * 32];
  const int tid = threadIdx.x;
  const int lane = tid & 63, wave = tid >> 6;
  const int wr = wave >> 1, wc = wave & 1;
  const int l15 = lane & 15, l16 = lane >> 4;
  const int tileM = blockIdx.y * 128, tileN = blockIdx.x * 128;
  f32x4 acc[4][4] = {};
  for (int k0 = 0; k0 < 1024; k0 += 32) {
#pragma unroll
    for (int p = 0; p < 2; ++p) {
      int c = tid + p * 256;
      int row = c >> 2, col = (c & 3) * 8;
      gload_lds16(A + (((size_t)(tileM + row)) << 10) + k0 + col, &As[c * 8]);
      gload_lds16(Bw + (((size_t)(tileN + row)) << 10) + k0 + col, &Bs[c * 8]);
    }
    __syncthreads();
    s16x8 af[4], bf[4];
#pragma unroll
    for (int i = 0; i < 4; ++i)
      af[i] = *(const s16x8*)&As[(wr * 64 + i * 16 + l15) * 32 + l16 * 8];
#pragma unroll
    for (int i = 0; i < 4; ++i)
      bf[i] = *(const s16x8*)&Bs[(wc * 64 + i * 16 + l15) * 32 + l16 * 8];
#pragma unroll
    for (int i = 0; i < 4; ++i)
#pragma unroll
      for (int j = 0; j < 4; ++j)
        acc[i][j] = __builtin_amdgcn_mfma_f32_16x16x32_bf16(af[i], bf[j], acc[i][j], 0, 0, 0);
    __syncthreads();
  }
#pragma unroll
  for (int i = 0; i < 4; ++i) {
#pragma unroll
    for (int j = 0; j < 4; ++j) {
      int n = tileN + wc * 64 + j * 16 + l15;
      float bv = bias[n];
#pragma unroll
      for (int r = 0; r < 4; ++r) {
        int m = tileM + wr * 64 + i * 16 + l16 * 4 + r;
        float v = acc[i][j][r] + bv;
        if (MODE == 0) {
          int b_ = m >> 11, s_ = m & 2047, h_ = n >> 6, d_ = n & 63;
          ((unsigned short*)Cout)[(((size_t)(b_ * H + h_) * S) + s_) * DK + d_] = f2bf(v);
        } else {
          ((float*)Cout)[(size_t)m * 1024 + n] = v;
        }
      }
    }
  }
}

// ---------------- V transpose: [bh][s][64] -> [bh][64][s] ----------------
__global__ __launch_bounds__(256) void k_transpose_v(const unsigned short* __restrict__ vstd,
                                                     unsigned short* __restrict__ vt) {
  __shared__ alignas(16) unsigned short T[64][72];
  int bh = blockIdx.y, st = blockIdx.x;
  int t = threadIdx.x;
  int rr = t >> 3, cc = (t & 7) * 8;
#pragma unroll
  for (int i = 0; i < 2; ++i) {
    int r = rr + i * 32;
    u16x8 v = *(const u16x8*)&vstd[((size_t)bh * S + st * 64 + r) * 64 + cc];
    *(u16x8*)&T[r][cc] = v;
  }
  __syncthreads();
#pragma unroll
  for (int i = 0; i < 2; ++i) {
    int d = rr + i * 32;
    u16x8 o;
#pragma unroll
    for (int j = 0; j < 8; ++j) o[j] = T[cc + j][d];
    *(u16x8*)&vt[((size_t)bh * 64 + d) * S + st * 64 + cc] = o;
  }
}

// ---------------- fused attention ----------------
// grid (32 q-tiles, 32 bh); 4 waves; wave handles 16 q-rows; 32-key steps.
// Ps rows are 128B so the (row&7)<<4 XOR swizzle stays inside the row
// (64B rows made the swizzle non-bijective: rows 7/8 collided -> round-1 bug).
__global__ __launch_bounds__(256) void k_attn(const unsigned short* __restrict__ qw,
                                              const unsigned short* __restrict__ kw,
                                              const unsigned short* __restrict__ vt,
                                              const int* __restrict__ mask,
                                              unsigned short* __restrict__ aout,
                                              float* __restrict__ attw) {
  __shared__ alignas(16) unsigned short Ks[32 * 64];
  __shared__ alignas(16) unsigned short Vs[64 * 32];
  __shared__ alignas(16) unsigned short Ps[4][16 * 64];
  const int bh = blockIdx.y;
  const int b = bh >> 4, h = bh & 15;
  const int q0 = blockIdx.x * 64;
  const int tid = threadIdx.x;
  const int lane = tid & 63, wave = tid >> 6;
  const int l15 = lane & 15, l16 = lane >> 4;
  const float scale = 0.125f;

  const int qrow = q0 + wave * 16 + l15;
  s16x8 qf0 = *(const s16x8*)&qw[((size_t)bh * S + qrow) * 64 + l16 * 8];
  s16x8 qf1 = *(const s16x8*)&qw[((size_t)bh * S + qrow) * 64 + 32 + l16 * 8];

  f32x4 oacc[4] = {};
  float lsum[4] = {0.f, 0.f, 0.f, 0.f};

  for (int kt = 0; kt < S / 32; ++kt) {
    {  // K tile: 32 rows x 64 bf16 (128B rows), XOR-swizzled source
      int c = tid, row = c >> 3, cc = (c & 7) ^ (row & 7);
      gload_lds16(&kw[((size_t)bh * S + kt * 32 + row) * 64 + cc * 8], &Ks[c * 8]);
    }
    {  // Vt tile: 64 rows x 32 bf16 (64B rows)
      int c = tid, row = c >> 2, cc = (c & 3) ^ (row & 3);
      gload_lds16(&vt[((size_t)bh * 64 + row) * S + kt * 32 + cc * 8], &Vs[c * 8]);
    }
    __syncthreads();

    f32x4 sac[2] = {};
#pragma unroll
    for (int nb = 0; nb < 2; ++nb) {
#pragma unroll
      for (int dc = 0; dc < 2; ++dc) {
        int row = nb * 16 + l15;
        int off = l16 * 16 + dc * 64;
        s16x8 kf = *(const s16x8*)((const char*)Ks + row * 128 + (off ^ ((row & 7) << 4)));
        sac[nb] = __builtin_amdgcn_mfma_f32_16x16x32_bf16(dc ? qf1 : qf0, kf, sac[nb], 0, 0, 0);
      }
    }

    float e[2][4];
#pragma unroll
    for (int nb = 0; nb < 2; ++nb) {
      int key = kt * 32 + nb * 16 + l15;
      int mk = mask[b * S + key];
#pragma unroll
      for (int r = 0; r < 4; ++r) e[nb][r] = mk ? __expf(sac[nb][r] * scale) : 0.f;
    }
#pragma unroll
    for (int r = 0; r < 4; ++r) {
      float t = e[0][r] + e[1][r];
      t += __shfl_xor(t, 1); t += __shfl_xor(t, 2);
      t += __shfl_xor(t, 4); t += __shfl_xor(t, 8);
      lsum[r] += t;
    }
    unsigned short* P = Ps[wave];
#pragma unroll
    for (int nb = 0; nb < 2; ++nb)
#pragma unroll
      for (int r = 0; r < 4; ++r) {
        int row = l16 * 4 + r, col = nb * 16 + l15;
        *(unsigned short*)((char*)P + row * 128 + ((col * 2) ^ ((row & 7) << 4))) = f2bf(e[nb][r]);
      }
    __syncthreads();
    s16x8 pf = *(const s16x8*)((const char*)P + l15 * 128 + ((l16 * 16) ^ ((l15 & 7) << 4)));
#pragma unroll
    for (int db = 0; db < 4; ++db) {
      int row = db * 16 + l15;
      s16x8 vf = *(const s16x8*)((const char*)Vs + row * 64 + ((l16 * 16) ^ ((row & 3) << 4)));
      oacc[db] = __builtin_amdgcn_mfma_f32_16x16x32_bf16(pf, vf, oacc[db], 0, 0, 0);
    }
    __syncthreads();
  }

  float invl[4];
#pragma unroll
  for (int r = 0; r < 4; ++r) invl[r] = 1.f / lsum[r];

#pragma unroll
  for (int db = 0; db < 4; ++db)
#pragma unroll
    for (int r = 0; r < 4; ++r) {
      int m = q0 + wave * 16 + l16 * 4 + r;
      int d = db * 16 + l15;
      aout[((size_t)b * S + m) * D + h * 64 + d] = f2bf(oacc[db][r] * invl[r]);
    }

  // Phase B: recompute scores, write normalized weights (fp32) to d_out.
  for (int kt = 0; kt < S / 32; ++kt) {
    {
      int c = tid, row = c >> 3, cc = (c & 7) ^ (row & 7);
      gload_lds16(&kw[((size_t)bh * S + kt * 32 + row) * 64 + cc * 8], &Ks[c * 8]);
    }
    __syncthreads();
    f32x4 sac[2] = {};
#pragma unroll
    for (int nb = 0; nb < 2; ++nb)
#pragma unroll
      for (int dc = 0; dc < 2; ++dc) {
        int row = nb * 16 + l15;
        int off = l16 * 16 + dc * 64;
        s16x8 kf = *(const s16x8*)((const char*)Ks + row * 128 + (off ^ ((row & 7) << 4)));
        sac[nb] = __builtin_amdgcn_mfma_f32_16x16x32_bf16(dc ? qf1 : qf0, kf, sac[nb], 0, 0, 0);
      }
#pragma unroll
    for (int nb = 0; nb < 2; ++nb) {
      int key = kt * 32 + nb * 16 + l15;
      int mk = mask[b * S + key];
#pragma unroll
      for (int r = 0; r < 4; ++r) {
        int m = q0 + wave * 16 + l16 * 4 + r;
        float w = mk ? __expf(sac[nb][r] * scale) * invl[r] : 0.f;
        attw[((size_t)bh * S + m) * S + key] = w;
      }
    }
    __syncthreads();
  }
}

// ---------------- host ----------------
extern "C" void kernel_launch(void* const* d_in, const int* in_sizes, int n_in,
                              void* d_out, int out_size, void* d_ws, size_t ws_size,
                              hipStream_t stream) {
  (void)in_sizes; (void)n_in; (void)out_size; (void)ws_size;
  const float* Q  = (const float*)d_in[0];
  const float* K  = (const float*)d_in[1];
  const float* V  = (const float*)d_in[2];
  const int* mask = (const int*)d_in[3];
  const float* bq = (const float*)d_in[5];
  const float* bk = (const float*)d_in[7];
  const float* bv = (const float*)d_in[9];
  const float* bo = (const float*)d_in[11];
  const float* Wq = (const float*)d_in[4];
  const float* Wk = (const float*)d_in[6];
  const float* Wv = (const float*)d_in[8];
  const float* Wo = (const float*)d_in[10];

  char* ws = (char*)d_ws;
  unsigned short* Xbf  = (unsigned short*)(ws + 0);           // [3][4096*1024] bf16
  unsigned short* Wbf  = (unsigned short*)(ws + 25165824);    // [4][1024*1024] bf16
  unsigned short* qws  = (unsigned short*)(ws + 33554432);    // [bh][s][64]
  unsigned short* kws  = (unsigned short*)(ws + 41943040);    // [bh][s][64]
  unsigned short* vstd = (unsigned short*)(ws + 50331648);    // [bh][s][64]
  unsigned short* vt   = (unsigned short*)(ws + 0);           // reuse Xbf[Q] (done)
  unsigned short* aoutb= (unsigned short*)(ws + 8388608);     // reuse Xbf[K] (done)
  float* out0 = (float*)d_out;
  float* attw = (float*)d_out + OUT0;

  k_cvt<<<dim3(2048), dim3(256), 0, stream>>>(Q, Xbf + 0,       524288);
  k_cvt<<<dim3(2048), dim3(256), 0, stream>>>(K, Xbf + 4194304, 524288);
  k_cvt<<<dim3(2048), dim3(256), 0, stream>>>(V, Xbf + 8388608, 524288);
  k_cvt<<<dim3(512),  dim3(256), 0, stream>>>(Wq, Wbf + 0,       131072);
  k_cvt<<<dim3(512),  dim3(256), 0, stream>>>(Wk, Wbf + 1048576, 131072);
  k_cvt<<<dim3(512),  dim3(256), 0, stream>>>(Wv, Wbf + 2097152, 131072);
  k_cvt<<<dim3(512),  dim3(256), 0, stream>>>(Wo, Wbf + 3145728, 131072);

  dim3 gg(8, 32);
  k_gemm<0><<<gg, dim3(256), 0, stream>>>(Xbf + 0,       Wbf + 0,       bq, qws);
  k_gemm<0><<<gg, dim3(256), 0, stream>>>(Xbf + 4194304, Wbf + 1048576, bk, kws);
  k_gemm<0><<<gg, dim3(256), 0, stream>>>(Xbf + 8388608, Wbf + 2097152, bv, vstd);

  k_transpose_v<<<dim3(32, 32), dim3(256), 0, stream>>>(vstd, vt);

  k_attn<<<dim3(32, 32), dim3(256), 0, stream>>>(qws, kws, vt, mask, aoutb, attw);

  k_gemm<1><<<gg, dim3(256), 0, stream>>>(aoutb, Wbf + 3145728, bo, out0);
}

// Round 3
// 303.073 us; speedup vs baseline: 1.2581x; 1.2581x over previous
//
#include <hip/hip_runtime.h>
#include <stdint.h>

#define DEVINL __device__ __forceinline__

typedef float  f32x4  __attribute__((ext_vector_type(4)));
typedef float  f32x16 __attribute__((ext_vector_type(16)));
typedef short  s16x8  __attribute__((ext_vector_type(8)));
typedef unsigned short u16x8 __attribute__((ext_vector_type(8)));

static constexpr int Bb = 2, S = 2048, D = 1024, H = 16, DK = 64;
static constexpr size_t OUT0 = (size_t)Bb * S * D;   // 4194304

DEVINL unsigned short f2bf(float f) {
  union { float f; unsigned u; } v; v.f = f;
  unsigned r = v.u + 0x7FFFu + ((v.u >> 16) & 1u);   // RNE
  return (unsigned short)(r >> 16);
}

DEVINL void gload_lds16(const void* g, void* l) {
  __builtin_amdgcn_global_load_lds(
      (const __attribute__((address_space(1))) unsigned int*)g,
      (__attribute__((address_space(3))) unsigned int*)l, 16, 0, 0);
}

// ---------------- fp32 -> bf16 converts (fused launches) ----------------
DEVINL void cvt_body(const float* __restrict__ src, unsigned short* __restrict__ dst, int i) {
  const f32x4* s4 = (const f32x4*)src;
  f32x4 a = s4[i * 2], b = s4[i * 2 + 1];
  u16x8 o;
  o[0] = f2bf(a[0]); o[1] = f2bf(a[1]); o[2] = f2bf(a[2]); o[3] = f2bf(a[3]);
  o[4] = f2bf(b[0]); o[5] = f2bf(b[1]); o[6] = f2bf(b[2]); o[7] = f2bf(b[3]);
  ((u16x8*)dst)[i] = o;
}

__global__ __launch_bounds__(256) void k_cvt3(const float* __restrict__ a, const float* __restrict__ b,
                                              const float* __restrict__ c,
                                              unsigned short* __restrict__ oa, unsigned short* __restrict__ ob,
                                              unsigned short* __restrict__ oc) {
  int z = blockIdx.y;
  const float* src = z == 0 ? a : z == 1 ? b : c;
  unsigned short* dst = z == 0 ? oa : z == 1 ? ob : oc;
  cvt_body(src, dst, blockIdx.x * 256 + threadIdx.x);
}

__global__ __launch_bounds__(256) void k_cvt4(const float* __restrict__ a, const float* __restrict__ b,
                                              const float* __restrict__ c, const float* __restrict__ d,
                                              unsigned short* __restrict__ oa, unsigned short* __restrict__ ob,
                                              unsigned short* __restrict__ oc, unsigned short* __restrict__ od) {
  int z = blockIdx.y;
  const float* src = z == 0 ? a : z == 1 ? b : z == 2 ? c : d;
  unsigned short* dst = z == 0 ? oa : z == 1 ? ob : z == 2 ? oc : od;
  cvt_body(src, dst, blockIdx.x * 256 + threadIdx.x);
}

// ---------------- GEMM core: C[128,128] tile of A[M,1024] @ W[N,1024]^T ----
// Epilogue MODE 0: bf16 to [b,h,s,d] with scale; MODE 1: fp32 row-major.
template <int MODE>
DEVINL void gemm_tile(const unsigned short* __restrict__ A,
                      const unsigned short* __restrict__ Bw,
                      const float* __restrict__ bias, void* __restrict__ Cout,
                      int tileM, int tileN, float scl,
                      unsigned short* As, unsigned short* Bs) {
  const int tid = threadIdx.x;
  const int lane = tid & 63, wave = tid >> 6;
  const int wr = wave >> 1, wc = wave & 1;
  const int l15 = lane & 15, l16 = lane >> 4;
  f32x4 acc[4][4] = {};
  for (int k0 = 0; k0 < 1024; k0 += 32) {
#pragma unroll
    for (int p = 0; p < 2; ++p) {
      int c = tid + p * 256;
      int row = c >> 2, col = (c & 3) * 8;
      gload_lds16(A + (((size_t)(tileM + row)) << 10) + k0 + col, &As[c * 8]);
      gload_lds16(Bw + (((size_t)(tileN + row)) << 10) + k0 + col, &Bs[c * 8]);
    }
    __syncthreads();
    s16x8 af[4], bf[4];
#pragma unroll
    for (int i = 0; i < 4; ++i)
      af[i] = *(const s16x8*)&As[(wr * 64 + i * 16 + l15) * 32 + l16 * 8];
#pragma unroll
    for (int i = 0; i < 4; ++i)
      bf[i] = *(const s16x8*)&Bs[(wc * 64 + i * 16 + l15) * 32 + l16 * 8];
#pragma unroll
    for (int i = 0; i < 4; ++i)
#pragma unroll
      for (int j = 0; j < 4; ++j)
        acc[i][j] = __builtin_amdgcn_mfma_f32_16x16x32_bf16(af[i], bf[j], acc[i][j], 0, 0, 0);
    __syncthreads();
  }
#pragma unroll
  for (int i = 0; i < 4; ++i) {
#pragma unroll
    for (int j = 0; j < 4; ++j) {
      int n = tileN + wc * 64 + j * 16 + l15;
      float bv = bias[n];
#pragma unroll
      for (int r = 0; r < 4; ++r) {
        int m = tileM + wr * 64 + i * 16 + l16 * 4 + r;
        float v = (acc[i][j][r] + bv) * scl;
        if (MODE == 0) {
          int b_ = m >> 11, s_ = m & 2047, h_ = n >> 6, d_ = n & 63;
          ((unsigned short*)Cout)[(((size_t)(b_ * H + h_) * S) + s_) * DK + d_] = f2bf(v);
        } else {
          ((float*)Cout)[(size_t)m * 1024 + n] = v;
        }
      }
    }
  }
}

// Fused QKV projection: grid (8, 32, 3). z=0 -> Q (pre-scaled by 1/8), z=1 -> K, z=2 -> V.
__global__ __launch_bounds__(256) void k_gemm_qkv(
    const unsigned short* __restrict__ Xq, const unsigned short* __restrict__ Xk,
    const unsigned short* __restrict__ Xv,
    const unsigned short* __restrict__ Wq, const unsigned short* __restrict__ Wk,
    const unsigned short* __restrict__ Wv,
    const float* __restrict__ bq, const float* __restrict__ bk, const float* __restrict__ bv,
    unsigned short* __restrict__ oq, unsigned short* __restrict__ ok, unsigned short* __restrict__ ov) {
  __shared__ alignas(16) unsigned short As[128 * 32];
  __shared__ alignas(16) unsigned short Bs[128 * 32];
  int z = blockIdx.z;
  const unsigned short* A = z == 0 ? Xq : z == 1 ? Xk : Xv;
  const unsigned short* W = z == 0 ? Wq : z == 1 ? Wk : Wv;
  const float* bias = z == 0 ? bq : z == 1 ? bk : bv;
  unsigned short* o = z == 0 ? oq : z == 1 ? ok : ov;
  float scl = z == 0 ? 0.125f : 1.0f;
  gemm_tile<0>(A, W, bias, o, blockIdx.y * 128, blockIdx.x * 128, scl, As, Bs);
}

// Output projection: grid (8, 32).
__global__ __launch_bounds__(256) void k_gemm_out(const unsigned short* __restrict__ A,
                                                  const unsigned short* __restrict__ W,
                                                  const float* __restrict__ bias,
                                                  float* __restrict__ Cout) {
  __shared__ alignas(16) unsigned short As[128 * 32];
  __shared__ alignas(16) unsigned short Bs[128 * 32];
  gemm_tile<1>(A, W, bias, Cout, blockIdx.y * 128, blockIdx.x * 128, 1.0f, As, Bs);
}

// ---------------- V transpose: [bh][s][64] -> [bh][64][s] ----------------
__global__ __launch_bounds__(256) void k_transpose_v(const unsigned short* __restrict__ vstd,
                                                     unsigned short* __restrict__ vt) {
  __shared__ alignas(16) unsigned short T[64][72];
  int bh = blockIdx.y, st = blockIdx.x;
  int t = threadIdx.x;
  int rr = t >> 3, cc = (t & 7) * 8;
#pragma unroll
  for (int i = 0; i < 2; ++i) {
    int r = rr + i * 32;
    u16x8 v = *(const u16x8*)&vstd[((size_t)bh * S + st * 64 + r) * 64 + cc];
    *(u16x8*)&T[r][cc] = v;
  }
  __syncthreads();
#pragma unroll
  for (int i = 0; i < 2; ++i) {
    int d = rr + i * 32;
    u16x8 o;
#pragma unroll
    for (int j = 0; j < 8; ++j) o[j] = T[cc + j][d];
    *(u16x8*)&vt[((size_t)bh * 64 + d) * S + st * 64 + cc] = o;
  }
}

// ---------------- fused attention, phase A only ----------------
// Q pre-scaled by 1/8. Computes O (bf16, [b,s,h,d] flattened to [b,s,D]) and
// log2(lsum) per (bh,row) into ws for k_weights.
__global__ __launch_bounds__(256) void k_attn(const unsigned short* __restrict__ qw,
                                              const unsigned short* __restrict__ kw,
                                              const unsigned short* __restrict__ vt,
                                              const int* __restrict__ mask,
                                              unsigned short* __restrict__ aout,
                                              float* __restrict__ l2lws) {
  __shared__ alignas(16) unsigned short Ks[32 * 64];
  __shared__ alignas(16) unsigned short Vs[64 * 32];
  __shared__ alignas(16) unsigned short Ps[4][16 * 64];
  const int bh = blockIdx.y;
  const int b = bh >> 4, h = bh & 15;
  const int q0 = blockIdx.x * 64;
  const int tid = threadIdx.x;
  const int lane = tid & 63, wave = tid >> 6;
  const int l15 = lane & 15, l16 = lane >> 4;

  const int qrow = q0 + wave * 16 + l15;
  s16x8 qf0 = *(const s16x8*)&qw[((size_t)bh * S + qrow) * 64 + l16 * 8];
  s16x8 qf1 = *(const s16x8*)&qw[((size_t)bh * S + qrow) * 64 + 32 + l16 * 8];

  f32x4 oacc[4] = {};
  float lsum[4] = {0.f, 0.f, 0.f, 0.f};

  for (int kt = 0; kt < S / 32; ++kt) {
    {  // K tile: 32 rows x 64 bf16 (128B rows), XOR-swizzled source
      int c = tid, row = c >> 3, cc = (c & 7) ^ (row & 7);
      gload_lds16(&kw[((size_t)bh * S + kt * 32 + row) * 64 + cc * 8], &Ks[c * 8]);
    }
    {  // Vt tile: 64 rows x 32 bf16 (64B rows)
      int c = tid, row = c >> 2, cc = (c & 3) ^ (row & 3);
      gload_lds16(&vt[((size_t)bh * 64 + row) * S + kt * 32 + cc * 8], &Vs[c * 8]);
    }
    __syncthreads();

    f32x4 sac[2] = {};
#pragma unroll
    for (int nb = 0; nb < 2; ++nb) {
#pragma unroll
      for (int dc = 0; dc < 2; ++dc) {
        int row = nb * 16 + l15;
        int off = l16 * 16 + dc * 64;
        s16x8 kf = *(const s16x8*)((const char*)Ks + row * 128 + (off ^ ((row & 7) << 4)));
        sac[nb] = __builtin_amdgcn_mfma_f32_16x16x32_bf16(dc ? qf1 : qf0, kf, sac[nb], 0, 0, 0);
      }
    }

    float e[2][4];
#pragma unroll
    for (int nb = 0; nb < 2; ++nb) {
      int key = kt * 32 + nb * 16 + l15;
      int mk = mask[b * S + key];
#pragma unroll
      for (int r = 0; r < 4; ++r) e[nb][r] = mk ? __expf(sac[nb][r]) : 0.f;
    }
#pragma unroll
    for (int r = 0; r < 4; ++r) {
      float t = e[0][r] + e[1][r];
      t += __shfl_xor(t, 1); t += __shfl_xor(t, 2);
      t += __shfl_xor(t, 4); t += __shfl_xor(t, 8);
      lsum[r] += t;
    }
    unsigned short* P = Ps[wave];
#pragma unroll
    for (int nb = 0; nb < 2; ++nb)
#pragma unroll
      for (int r = 0; r < 4; ++r) {
        int row = l16 * 4 + r, col = nb * 16 + l15;
        *(unsigned short*)((char*)P + row * 128 + ((col * 2) ^ ((row & 7) << 4))) = f2bf(e[nb][r]);
      }
    __syncthreads();
    s16x8 pf = *(const s16x8*)((const char*)P + l15 * 128 + ((l16 * 16) ^ ((l15 & 7) << 4)));
#pragma unroll
    for (int db = 0; db < 4; ++db) {
      int row = db * 16 + l15;
      s16x8 vf = *(const s16x8*)((const char*)Vs + row * 64 + ((l16 * 16) ^ ((row & 3) << 4)));
      oacc[db] = __builtin_amdgcn_mfma_f32_16x16x32_bf16(pf, vf, oacc[db], 0, 0, 0);
    }
    __syncthreads();
  }

  float invl[4];
#pragma unroll
  for (int r = 0; r < 4; ++r) invl[r] = 1.f / lsum[r];

  if (l15 == 0) {
#pragma unroll
    for (int r = 0; r < 4; ++r)
      l2lws[(size_t)bh * S + q0 + wave * 16 + l16 * 4 + r] = log2f(lsum[r]);
  }

#pragma unroll
  for (int db = 0; db < 4; ++db)
#pragma unroll
    for (int r = 0; r < 4; ++r) {
      int m = q0 + wave * 16 + l16 * 4 + r;
      int d = db * 16 + l15;
      aout[((size_t)b * S + m) * D + h * 64 + d] = f2bf(oacc[db][r] * invl[r]);
    }
}

// ---------------- attention weights (streaming, barrier-free) ----------------
// grid (S/32 = 64 q-tiles, 32 bh), 4 waves. Each wave: 32x32 score tile via
// mfma_32x32x16, keys stride 128 across waves. w = exp2(s*log2e - log2(lsum)).
// Nontemporal 128B-contiguous stores (32 lanes x 4B per row group).
__global__ __launch_bounds__(256) void k_weights(const unsigned short* __restrict__ qw,
                                                 const unsigned short* __restrict__ kw,
                                                 const int* __restrict__ mask,
                                                 const float* __restrict__ l2lws,
                                                 float* __restrict__ attw) {
  const int bh = blockIdx.y, b = bh >> 4;
  const int q0 = blockIdx.x * 32;
  const int lane = threadIdx.x & 63, wave = threadIdx.x >> 6;
  const int l31 = lane & 31, l32 = lane >> 5;
  const float LOG2E = 1.44269504f;

  s16x8 qa[4];
  const unsigned short* qbase = qw + ((size_t)bh * S + q0 + l31) * 64 + l32 * 8;
#pragma unroll
  for (int kc = 0; kc < 4; ++kc) qa[kc] = *(const s16x8*)(qbase + kc * 16);

  float nl2l[16];
#pragma unroll
  for (int r = 0; r < 16; ++r) {
    int row = (r & 3) + 8 * (r >> 2) + 4 * l32;
    nl2l[r] = l2lws[(size_t)bh * S + q0 + row];
  }

  for (int it = 0; it < 16; ++it) {
    int key0 = it * 128 + wave * 32;
    const unsigned short* kbase = kw + ((size_t)bh * S + key0 + l31) * 64 + l32 * 8;
    s16x8 kb[4];
#pragma unroll
    for (int kc = 0; kc < 4; ++kc) kb[kc] = *(const s16x8*)(kbase + kc * 16);
    f32x16 dacc = {};
#pragma unroll
    for (int kc = 0; kc < 4; ++kc)
      dacc = __builtin_amdgcn_mfma_f32_32x32x16_bf16(qa[kc], kb[kc], dacc, 0, 0, 0);

    int key = key0 + l31;
    int mk = mask[b * S + key];
    float* obase = attw + ((size_t)bh * S + q0) * S + key;
#pragma unroll
    for (int r = 0; r < 16; ++r) {
      int row = (r & 3) + 8 * (r >> 2) + 4 * l32;
      float w = mk ? exp2f(dacc[r] * LOG2E - nl2l[r]) : 0.f;
      __builtin_nontemporal_store(w, obase + (size_t)row * S);
    }
  }
}

// ---------------- host ----------------
extern "C" void kernel_launch(void* const* d_in, const int* in_sizes, int n_in,
                              void* d_out, int out_size, void* d_ws, size_t ws_size,
                              hipStream_t stream) {
  (void)in_sizes; (void)n_in; (void)out_size; (void)ws_size;
  const float* Q  = (const float*)d_in[0];
  const float* K  = (const float*)d_in[1];
  const float* V  = (const float*)d_in[2];
  const int* mask = (const int*)d_in[3];
  const float* Wq = (const float*)d_in[4];
  const float* bq = (const float*)d_in[5];
  const float* Wk = (const float*)d_in[6];
  const float* bk = (const float*)d_in[7];
  const float* Wv = (const float*)d_in[8];
  const float* bv = (const float*)d_in[9];
  const float* Wo = (const float*)d_in[10];
  const float* bo = (const float*)d_in[11];

  char* ws = (char*)d_ws;
  unsigned short* Xbf  = (unsigned short*)(ws + 0);           // [3][4194304] bf16
  unsigned short* Wbf  = (unsigned short*)(ws + 25165824);    // [4][1048576] bf16
  unsigned short* qws  = (unsigned short*)(ws + 33554432);    // [bh][s][64]
  unsigned short* kws  = (unsigned short*)(ws + 41943040);    // [bh][s][64]
  unsigned short* vstd = (unsigned short*)(ws + 50331648);    // [bh][s][64]
  float*          l2l  = (float*)(ws + 58720256);             // [32][2048] fp32
  unsigned short* vt   = (unsigned short*)(ws + 0);           // reuse Xbf[Q] (consumed)
  unsigned short* aoutb= (unsigned short*)(ws + 8388608);     // reuse Xbf[K] (consumed)
  float* out0 = (float*)d_out;
  float* attw = (float*)d_out + OUT0;

  k_cvt3<<<dim3(2048, 3), dim3(256), 0, stream>>>(Q, K, V, Xbf, Xbf + 4194304, Xbf + 8388608);
  k_cvt4<<<dim3(512, 4), dim3(256), 0, stream>>>(Wq, Wk, Wv, Wo,
                                                 Wbf, Wbf + 1048576, Wbf + 2097152, Wbf + 3145728);

  k_gemm_qkv<<<dim3(8, 32, 3), dim3(256), 0, stream>>>(
      Xbf, Xbf + 4194304, Xbf + 8388608,
      Wbf, Wbf + 1048576, Wbf + 2097152,
      bq, bk, bv, qws, kws, vstd);

  k_transpose_v<<<dim3(32, 32), dim3(256), 0, stream>>>(vstd, vt);

  k_attn<<<dim3(32, 32), dim3(256), 0, stream>>>(qws, kws, vt, mask, aoutb, l2l);

  k_weights<<<dim3(64, 32), dim3(256), 0, stream>>>(qws, kws, mask, l2l, attw);

  k_gemm_out<<<dim3(8, 32), dim3(256), 0, stream>>>(aoutb, Wbf + 3145728, bo, out0);
}